// Round 15
// baseline (301.994 us; speedup 1.0000x reference)
//
#include <hip/hip_runtime.h>
#include <hip/hip_bf16.h>

#define B_SZ     32
#define IN_DIM   1024
#define K_TOTAL  525824          // 1024 linear + 524800 triu = 4108 * 128
#define OUT_DIM  512
#define NCH      4108            // 128-k chunks
#define NPAIR    2054            // 256-k pairs
#define KGN      128             // number of k-blocks (contiguous pair ranges)
#define F_BYTES  ((size_t)NCH * 8192)            // 33,652,736 packed bf16 features
#define P_ELEMS  ((size_t)KGN * B_SZ * OUT_DIM)  // 128 * 16384 partials
#define NEED_WS  (F_BYTES + P_ELEMS * 4)

typedef __attribute__((ext_vector_type(8))) short bfrag;   // 8 bf16 = 4 VGPR
typedef __attribute__((ext_vector_type(4))) float f32x4;

// async global->LDS, 16B per lane; LDS dest = wave-uniform base + lane*16
#define GLD16(g, l) __builtin_amdgcn_global_load_lds(                      \
    (const __attribute__((address_space(1))) void*)(g),                    \
    (__attribute__((address_space(3))) void*)(l), 16, 0, 0)

// fp32 -> bf16 round-to-nearest-even (pure integer)
__device__ inline unsigned bf16r(float f)
{
    unsigned u = __builtin_bit_cast(unsigned, f);
    return (u + 0x7FFFu + ((u >> 16) & 1u)) >> 16;
}
__device__ inline unsigned pk2(float a, float b)
{
    return bf16r(a) | (bf16r(b) << 16);
}

// ---------------------------------------------------------------- bias init (fallback path only)
__global__ void bias_init_kernel(const float* __restrict__ bias, float* __restrict__ out)
{
    int i = blockIdx.x * 256 + threadIdx.x;     // 16384 total
    out[i] = bias[i & (OUT_DIM - 1)];
}

// ------------- kernel A: feature expand -> bf16, MFMA-A-fragment packed
// layout: unit u = (chunk*16 + koctet)*32 + b holds f[b][chunk*128+koctet*8 .. +7]
__global__ __launch_bounds__(256)
void feat_pack_kernel(const float* __restrict__ x, int4* __restrict__ fp)
{
    const int chunk = blockIdx.x;               // 0..4107
    const int tid   = threadIdx.x;

    #pragma unroll
    for (int i = 0; i < 2; ++i) {
        const int unit = tid + i * 256;         // 0..511
        const int kb   = unit >> 5;             // k-octet 0..15
        const int b    = unit & 31;
        const int k0   = chunk * 128 + kb * 8;
        const float* xb = x + b * IN_DIM;

        float v[8];
        if (chunk < 8) {                        // linear features (k < 1024)
            #pragma unroll
            for (int e = 0; e < 8; ++e) v[e] = xb[k0 + e];
        } else {                                // quadratic: walk (r,c) from one sqrt
            int t = k0 - IN_DIM;
            float disc = 4198401.0f - 8.0f * (float)t;   // 2049^2 - 8t, exact in fp32
            int r = (int)((2049.0f - sqrtf(disc)) * 0.5f);
            int off = r * IN_DIM - ((r * (r - 1)) >> 1);
            if (t < off) { --r; off = r * IN_DIM - ((r * (r - 1)) >> 1); }
            else if (t >= off + (IN_DIM - r)) { off += IN_DIM - r; ++r; }
            int c_ = r + (t - off);
            #pragma unroll
            for (int e = 0; e < 8; ++e) {
                v[e] = xb[r] * xb[c_];
                if (c_ == IN_DIM - 1) { ++r; c_ = r; } else { ++c_; }
            }
        }
        int4 pk;
        pk.x = (int)pk2(v[0], v[1]);
        pk.y = (int)pk2(v[2], v[3]);
        pk.z = (int)pk2(v[4], v[5]);
        pk.w = (int)pk2(v[6], v[7]);
        fp[(size_t)chunk * 512 + unit] = pk;
    }
}

// ------------- kernel B: MFMA GEMM, blocked-K contiguous streams.
// Block kg owns pairs [start, start+n): per W row a sequential 16-17 KB
// stream (1 KB burst per period, address-ordered) -> DRAM activates amortized.
// Wave = one o-16-tile; block = 4 waves sharing f-LDS; split-K partial store.
__global__ __launch_bounds__(256, 2)            // cap 256 VGPR: spill-proof
void qgemm_mfma_kernel(const int4* __restrict__ fp,
                       const float* __restrict__ W,
                       float* __restrict__ partial)
{
    __shared__ int4 fbuf[3][1024];               // 3 x 16 KB (pair tiles)

    const int tid  = threadIdx.x;
    const int lane = tid & 63;
    const int wv_  = tid >> 6;                   // 0..3
    const int lrow = lane & 15;                  // A row / B col within tile
    const int lkb  = lane >> 4;                  // k-octet group 0..3

    const int og = blockIdx.x >> 7;              // 0..7
    const int kg = blockIdx.x & (KGN - 1);       // 0..127 (same-kg blocks co-XCD)

    const int o_base = og * 64 + wv_ * 16;
    const float* wlane = W + (size_t)(o_base + lrow) * K_TOTAL;
    const char*  fpB   = (const char*)fp + (size_t)lane * 16;

    f32x4 acc0 = {0.f, 0.f, 0.f, 0.f};
    f32x4 acc1 = {0.f, 0.f, 0.f, 0.f};
    float4 wn[16];                               // fp32 prefetch (pair)
    int4   wcb[8];                               // bf16 fragments (pair)

    // load W for pair pp: per row 1 KB contiguous, issued back-to-back
    #define WLOADP(pp)                                                          \
    do {                                                                        \
        const float* wp_ = wlane + (size_t)(pp) * 256 + lkb * 8;                \
        _Pragma("unroll")                                                       \
        for (int q_ = 0; q_ < 4; ++q_) {                                        \
            wn[2*q_]   = *(const float4*)(wp_ + q_ * 32);                       \
            wn[2*q_+1] = *(const float4*)(wp_ + q_ * 32 + 4);                   \
        }                                                                       \
        _Pragma("unroll")                                                       \
        for (int q_ = 0; q_ < 4; ++q_) {                                        \
            wn[8+2*q_]   = *(const float4*)(wp_ + 128 + q_ * 32);               \
            wn[8+2*q_+1] = *(const float4*)(wp_ + 128 + q_ * 32 + 4);           \
        }                                                                       \
    } while (0)

    // stage f pair pp (16 KB contiguous) into buffer s
    #define STAGEF(s, pp)                                                       \
    do {                                                                        \
        const char* gp_ = fpB + (size_t)(pp) * 16384 + wv_ * 4096;              \
        _Pragma("unroll")                                                       \
        for (int j_ = 0; j_ < 4; ++j_)                                          \
            GLD16(gp_ + j_ * 1024, (char*)&fbuf[s][0] + wv_ * 4096 + j_ * 1024);\
    } while (0)

    // convert the fp32 prefetch (current pair) into bf16 fragments
    #define CVTW()                                                              \
    do {                                                                        \
        _Pragma("unroll")                                                       \
        for (int e_ = 0; e_ < 8; ++e_) {                                        \
            int4 tw_;                                                           \
            tw_.x = (int)pk2(wn[2*e_].x,   wn[2*e_].y);                         \
            tw_.y = (int)pk2(wn[2*e_].z,   wn[2*e_].w);                         \
            tw_.z = (int)pk2(wn[2*e_+1].x, wn[2*e_+1].y);                       \
            tw_.w = (int)pk2(wn[2*e_+1].z, wn[2*e_+1].w);                       \
            wcb[e_] = tw_;                                                      \
        }                                                                       \
    } while (0)

    #define COMPUTE(cbuf)                                                       \
    do {                                                                        \
        const int4* bp_ = &fbuf[cbuf][0];                                       \
        _Pragma("unroll")                                                       \
        for (int s_ = 0; s_ < 2; ++s_)                                          \
            _Pragma("unroll")                                                   \
            for (int q_ = 0; q_ < 4; ++q_) {                                    \
                const bfrag bw_ = __builtin_bit_cast(bfrag, wcb[s_*4 + q_]);    \
                const int ub_ = s_ * 512 + (q_ * 4 + lkb) * 32 + lrow;          \
                const bfrag a0_ = __builtin_bit_cast(bfrag, bp_[ub_]);          \
                const bfrag a1_ = __builtin_bit_cast(bfrag, bp_[ub_ + 16]);     \
                acc0 = __builtin_amdgcn_mfma_f32_16x16x32_bf16(a0_, bw_, acc0, 0, 0, 0); \
                acc1 = __builtin_amdgcn_mfma_f32_16x16x32_bf16(a1_, bw_, acc1, 0, 0, 0); \
            }                                                                   \
    } while (0)

    // blocked-K: contiguous pair range [start, start+n); 2054 = 6*17 + 122*16
    const int n     = (kg < 6) ? 17 : 16;
    const int start = (kg < 6) ? kg * 17 : kg * 16 + 6;
    int pc = start;

    STAGEF(0, pc);                               // f(p0) x4
    WLOADP(pc);                                  // W(p0) x16
    STAGEF(1, pc + 1);                           // f(p1) x4   -> 24 in flight

    int cb = 0, sb = 2;
    for (int t = 0; t < n; ++t) {
        asm volatile("s_waitcnt vmcnt(4)" ::: "memory");   // f(t),W(t) landed; f(t+1) may fly
        __builtin_amdgcn_s_barrier();            // all waves past COMPUTE(t-1)
        CVTW();                                  // wn -> wcb, frees wn
        const int pw = (t + 1 < n) ? pc + 1 : pc;          // clamped re-reads harmless
        const int pf = (t + 2 < n) ? pc + 2 : pw;
        WLOADP(pw);
        STAGEF(sb, pf);
        COMPUTE(cb);
        cb = (cb == 2) ? 0 : cb + 1;
        sb = (sb == 2) ? 0 : sb + 1;
        pc += 1;
    }
    asm volatile("s_waitcnt vmcnt(0)" ::: "memory");       // drain DMA before exit

    #undef COMPUTE
    #undef CVTW
    #undef STAGEF
    #undef WLOADP

    // C layout: C[b = (lane>>4)*4 + reg][o = lane&15]; plain stores to partial[kg]
    float* pb = partial + (size_t)kg * (B_SZ * OUT_DIM) + o_base + lrow;
    const int r0 = lkb * 4;
    #pragma unroll
    for (int r = 0; r < 4; ++r) {
        pb[(size_t)(r0 + r) * OUT_DIM]      = acc0[r];
        pb[(size_t)(16 + r0 + r) * OUT_DIM] = acc1[r];
    }
}

// ------------- kernel C: reduce 128 partials + bias -> out
__global__ __launch_bounds__(256)
void reduce_kernel(const float* __restrict__ partial,
                   const float* __restrict__ bias,
                   float* __restrict__ out)
{
    const int idx = blockIdx.x * 256 + threadIdx.x;   // 0..16383
    float s = bias[idx & (OUT_DIM - 1)];
    const float* p = partial + idx;
    #pragma unroll 8
    for (int kg = 0; kg < KGN; ++kg)
        s += p[(size_t)kg * (B_SZ * OUT_DIM)];
    out[idx] = s;
}

// ------------------------------------------------- fallback (proven v2 path)
__global__ __launch_bounds__(512, 2)
void qgemm_fallback_kernel(const float* __restrict__ x,
                           const float* __restrict__ W,
                           float* __restrict__ out)
{
    __shared__ float xt[B_SZ][512];

    const int tid  = threadIdx.x;
    const int lane = tid & 63;
    const int wave = tid >> 6;
    const int bgrp = wave & 3;
    const int ogrp = wave >> 2;

    const int og  = blockIdx.x & 31;
    const int kgf = blockIdx.x >> 5;

    const int o_base = og * 16 + ogrp * 8;
    const int b_base = bgrp * 8;

    float acc[8][8];
    #pragma unroll
    for (int i = 0; i < 8; ++i)
        #pragma unroll
        for (int o = 0; o < 8; ++o) acc[i][o] = 0.f;

    const int nch = (K_TOTAL + 511) / 512;
    for (int chunk = kgf; chunk < nch; chunk += 16) {
        const int k = chunk * 512 + tid;
        __syncthreads();
        if (k < IN_DIM) {
            #pragma unroll
            for (int b = 0; b < B_SZ; ++b)
                xt[b][tid] = x[b * IN_DIM + k];
        } else {
            const int t = k - IN_DIM;
            double disc = 4198401.0 - 8.0 * (double)t;
            int r = (int)((2049.0 - sqrt(disc)) * 0.5);
            int off = r * IN_DIM - ((r * (r - 1)) >> 1);
            if (t < off) { --r; off = r * IN_DIM - ((r * (r - 1)) >> 1); }
            else if (t >= off + (IN_DIM - r)) { off += IN_DIM - r; ++r; }
            const int ccol = r + (t - off);
            #pragma unroll
            for (int b = 0; b < B_SZ; ++b)
                xt[b][tid] = x[b * IN_DIM + r] * x[b * IN_DIM + ccol];
        }
        __syncthreads();

        const float* wrow = W + (size_t)o_base * K_TOTAL + (size_t)chunk * 512;
        #pragma unroll
        for (int pass = 0; pass < 2; ++pass) {
            const int kk = pass * 256 + lane * 4;
            float4 wv[8];
            #pragma unroll
            for (int o = 0; o < 8; ++o)
                wv[o] = *(const float4*)(wrow + (size_t)o * K_TOTAL + kk);
            float4 xv[8];
            #pragma unroll
            for (int i = 0; i < 8; ++i)
                xv[i] = *(const float4*)&xt[b_base + i][kk];
            #pragma unroll
            for (int o = 0; o < 8; ++o)
                #pragma unroll
                for (int i = 0; i < 8; ++i)
                    acc[i][o] += xv[i].x * wv[o].x + xv[i].y * wv[o].y
                               + xv[i].z * wv[o].z + xv[i].w * wv[o].w;
        }
    }

    #pragma unroll
    for (int i = 0; i < 8; ++i)
        #pragma unroll
        for (int o = 0; o < 8; ++o) {
            float v = acc[i][o];
            #pragma unroll
            for (int m = 1; m < 64; m <<= 1)
                v += __shfl_xor(v, m);
            acc[i][o] = v;
        }

    if (lane == 0) {
        #pragma unroll
        for (int i = 0; i < 8; ++i)
            #pragma unroll
            for (int o = 0; o < 8; ++o)
                atomicAdd(&out[(b_base + i) * OUT_DIM + o_base + o], acc[i][o]);
    }
}

extern "C" void kernel_launch(void* const* d_in, const int* in_sizes, int n_in,
                              void* d_out, int out_size, void* d_ws, size_t ws_size,
                              hipStream_t stream)
{
    const float* x    = (const float*)d_in[0];   // [32,1024] fp32
    const float* W    = (const float*)d_in[1];   // [512, 525824] fp32
    const float* bias = (const float*)d_in[2];   // [512] fp32
    float* out = (float*)d_out;                  // [32,512] fp32

    if (ws_size >= NEED_WS) {
        int4*  fpk  = (int4*)d_ws;
        float* part = (float*)((char*)d_ws + F_BYTES);
        hipLaunchKernelGGL(feat_pack_kernel, dim3(NCH), dim3(256), 0, stream, x, fpk);
        hipLaunchKernelGGL(qgemm_mfma_kernel, dim3(8 * KGN), dim3(256), 0, stream,
                           fpk, W, part);
        hipLaunchKernelGGL(reduce_kernel, dim3(64), dim3(256), 0, stream,
                           part, bias, out);
    } else {
        hipLaunchKernelGGL(bias_init_kernel, dim3(64), dim3(256), 0, stream, bias, out);
        hipLaunchKernelGGL(qgemm_fallback_kernel, dim3(512), dim3(512), 0, stream,
                           x, W, out);
    }
}

// Round 16
// 281.946 us; speedup vs baseline: 1.0711x; 1.0711x over previous
//
#include <hip/hip_runtime.h>
#include <hip/hip_bf16.h>

#define B_SZ     32
#define IN_DIM   1024
#define K_TOTAL  525824          // 1024 linear + 524800 triu = 4108 * 128
#define OUT_DIM  512
#define NCH      4108            // 128-k chunks
#define NPAIR    2054            // 256-k pairs
#define KGN      128             // pair-group count (pair stride)
#define F_BYTES  ((size_t)NCH * 8192)            // 33,652,736 packed bf16 features
#define P_ELEMS  ((size_t)KGN * B_SZ * OUT_DIM)  // 128 * 16384 partials
#define NEED_WS  (F_BYTES + P_ELEMS * 4)

typedef __attribute__((ext_vector_type(8))) short bfrag;   // 8 bf16 = 4 VGPR
typedef __attribute__((ext_vector_type(4))) float f32x4;

// async global->LDS, 16B per lane; LDS dest = wave-uniform base + lane*16
#define GLD16(g, l) __builtin_amdgcn_global_load_lds(                      \
    (const __attribute__((address_space(1))) void*)(g),                    \
    (__attribute__((address_space(3))) void*)(l), 16, 0, 0)

// fp32 -> bf16 round-to-nearest-even (pure integer)
__device__ inline unsigned bf16r(float f)
{
    unsigned u = __builtin_bit_cast(unsigned, f);
    return (u + 0x7FFFu + ((u >> 16) & 1u)) >> 16;
}
__device__ inline unsigned pk2(float a, float b)
{
    return bf16r(a) | (bf16r(b) << 16);
}

// ---------------------------------------------------------------- bias init (fallback path only)
__global__ void bias_init_kernel(const float* __restrict__ bias, float* __restrict__ out)
{
    int i = blockIdx.x * 256 + threadIdx.x;     // 16384 total
    out[i] = bias[i & (OUT_DIM - 1)];
}

// ------------- kernel A: feature expand -> bf16, MFMA-A-fragment packed
// layout: unit u = (chunk*16 + koctet)*32 + b holds f[b][chunk*128+koctet*8 .. +7]
__global__ __launch_bounds__(256)
void feat_pack_kernel(const float* __restrict__ x, int4* __restrict__ fp)
{
    const int chunk = blockIdx.x;               // 0..4107
    const int tid   = threadIdx.x;

    #pragma unroll
    for (int i = 0; i < 2; ++i) {
        const int unit = tid + i * 256;         // 0..511
        const int kb   = unit >> 5;             // k-octet 0..15
        const int b    = unit & 31;
        const int k0   = chunk * 128 + kb * 8;
        const float* xb = x + b * IN_DIM;

        float v[8];
        if (chunk < 8) {                        // linear features (k < 1024)
            #pragma unroll
            for (int e = 0; e < 8; ++e) v[e] = xb[k0 + e];
        } else {                                // quadratic: walk (r,c) from one sqrt
            int t = k0 - IN_DIM;
            float disc = 4198401.0f - 8.0f * (float)t;   // 2049^2 - 8t, exact in fp32
            int r = (int)((2049.0f - sqrtf(disc)) * 0.5f);
            int off = r * IN_DIM - ((r * (r - 1)) >> 1);
            if (t < off) { --r; off = r * IN_DIM - ((r * (r - 1)) >> 1); }
            else if (t >= off + (IN_DIM - r)) { off += IN_DIM - r; ++r; }
            int c_ = r + (t - off);
            #pragma unroll
            for (int e = 0; e < 8; ++e) {
                v[e] = xb[r] * xb[c_];
                if (c_ == IN_DIM - 1) { ++r; c_ = r; } else { ++c_; }
            }
        }
        int4 pk;
        pk.x = (int)pk2(v[0], v[1]);
        pk.y = (int)pk2(v[2], v[3]);
        pk.z = (int)pk2(v[4], v[5]);
        pk.w = (int)pk2(v[6], v[7]);
        fp[(size_t)chunk * 512 + unit] = pk;
    }
}

// ------------- kernel B: MFMA GEMM, pair-chunk periods (1 KB W spans/row),
// strided pair ownership (v14 mapping), 3 blocks/CU for barrier-phase overlap.
// Wave = one o-16-tile x one pair-segment; block = 4 waves sharing f-LDS.
__global__ __launch_bounds__(256, 3)            // cap ~170 VGPR, 3 blocks/CU
void qgemm_mfma_kernel(const int4* __restrict__ fp,
                       const float* __restrict__ W,
                       float* __restrict__ partial)
{
    __shared__ int4 fbuf[3][1024];               // 3 x 16 KB (pair tiles)

    const int tid  = threadIdx.x;
    const int lane = tid & 63;
    const int wv_  = tid >> 6;                   // 0..3
    const int lrow = lane & 15;                  // A row / B col within tile
    const int lkb  = lane >> 4;                  // k-octet group 0..3

    const int og = blockIdx.x >> 7;              // 0..7
    const int kg = blockIdx.x & (KGN - 1);       // 0..127 (bid%8 = kg%8: co-XCD f sharing)

    const int o_base = og * 64 + wv_ * 16;
    const float* wlane = W + (size_t)(o_base + lrow) * K_TOTAL;
    const char*  fpB   = (const char*)fp + (size_t)lane * 16;

    f32x4 acc0 = {0.f, 0.f, 0.f, 0.f};
    f32x4 acc1 = {0.f, 0.f, 0.f, 0.f};
    float4 wn[16];                               // fp32 prefetch (pair)
    int4   wcb[8];                               // bf16 fragments (pair)

    // load W for pair pp: per row 1 KB contiguous, issued back-to-back
    #define WLOADP(pp)                                                          \
    do {                                                                        \
        const float* wp_ = wlane + (size_t)(pp) * 256 + lkb * 8;                \
        _Pragma("unroll")                                                       \
        for (int q_ = 0; q_ < 4; ++q_) {                                        \
            wn[2*q_]   = *(const float4*)(wp_ + q_ * 32);                       \
            wn[2*q_+1] = *(const float4*)(wp_ + q_ * 32 + 4);                   \
        }                                                                       \
        _Pragma("unroll")                                                       \
        for (int q_ = 0; q_ < 4; ++q_) {                                        \
            wn[8+2*q_]   = *(const float4*)(wp_ + 128 + q_ * 32);               \
            wn[8+2*q_+1] = *(const float4*)(wp_ + 128 + q_ * 32 + 4);           \
        }                                                                       \
    } while (0)

    // stage f pair pp (16 KB contiguous) into buffer s
    #define STAGEF(s, pp)                                                       \
    do {                                                                        \
        const char* gp_ = fpB + (size_t)(pp) * 16384 + wv_ * 4096;              \
        _Pragma("unroll")                                                       \
        for (int j_ = 0; j_ < 4; ++j_)                                          \
            GLD16(gp_ + j_ * 1024, (char*)&fbuf[s][0] + wv_ * 4096 + j_ * 1024);\
    } while (0)

    // convert the fp32 prefetch (current pair) into bf16 fragments
    #define CVTW()                                                              \
    do {                                                                        \
        _Pragma("unroll")                                                       \
        for (int e_ = 0; e_ < 8; ++e_) {                                        \
            int4 tw_;                                                           \
            tw_.x = (int)pk2(wn[2*e_].x,   wn[2*e_].y);                         \
            tw_.y = (int)pk2(wn[2*e_].z,   wn[2*e_].w);                         \
            tw_.z = (int)pk2(wn[2*e_+1].x, wn[2*e_+1].y);                       \
            tw_.w = (int)pk2(wn[2*e_+1].z, wn[2*e_+1].w);                       \
            wcb[e_] = tw_;                                                      \
        }                                                                       \
    } while (0)

    #define COMPUTE(cbuf)                                                       \
    do {                                                                        \
        const int4* bp_ = &fbuf[cbuf][0];                                       \
        _Pragma("unroll")                                                       \
        for (int s_ = 0; s_ < 2; ++s_)                                          \
            _Pragma("unroll")                                                   \
            for (int q_ = 0; q_ < 4; ++q_) {                                    \
                const bfrag bw_ = __builtin_bit_cast(bfrag, wcb[s_*4 + q_]);    \
                const int ub_ = s_ * 512 + (q_ * 4 + lkb) * 32 + lrow;          \
                const bfrag a0_ = __builtin_bit_cast(bfrag, bp_[ub_]);          \
                const bfrag a1_ = __builtin_bit_cast(bfrag, bp_[ub_ + 16]);     \
                acc0 = __builtin_amdgcn_mfma_f32_16x16x32_bf16(a0_, bw_, acc0, 0, 0, 0); \
                acc1 = __builtin_amdgcn_mfma_f32_16x16x32_bf16(a1_, bw_, acc1, 0, 0, 0); \
            }                                                                   \
    } while (0)

    const int n  = 16 + (kg < 6 ? 1 : 0);        // pairs owned: kg + t*128 < 2054
    int pc = kg;

    STAGEF(0, pc);                               // f(p0) x4
    WLOADP(pc);                                  // W(p0) x16
    STAGEF(1, pc + KGN);                         // f(p1) x4   -> 24 in flight

    int cb = 0, sb = 2;
    for (int t = 0; t < n; ++t) {
        asm volatile("s_waitcnt vmcnt(4)" ::: "memory");   // f(t),W(t) landed; f(t+1) may fly
        __builtin_amdgcn_s_barrier();            // all waves past COMPUTE(t-1)
        CVTW();                                  // wn -> wcb, frees wn
        const int pw = (t + 1 < n) ? pc + KGN     : pc;    // clamped re-reads are harmless
        const int pf = (t + 2 < n) ? pc + 2 * KGN : pw;
        WLOADP(pw);
        STAGEF(sb, pf);
        COMPUTE(cb);
        cb = (cb == 2) ? 0 : cb + 1;
        sb = (sb == 2) ? 0 : sb + 1;
        pc += KGN;
    }
    asm volatile("s_waitcnt vmcnt(0)" ::: "memory");       // drain DMA before exit

    #undef COMPUTE
    #undef CVTW
    #undef STAGEF
    #undef WLOADP

    // C layout: C[b = (lane>>4)*4 + reg][o = lane&15]; plain stores to partial[kg]
    float* pb = partial + (size_t)kg * (B_SZ * OUT_DIM) + o_base + lrow;
    const int r0 = lkb * 4;
    #pragma unroll
    for (int r = 0; r < 4; ++r) {
        pb[(size_t)(r0 + r) * OUT_DIM]      = acc0[r];
        pb[(size_t)(16 + r0 + r) * OUT_DIM] = acc1[r];
    }
}

// ------------- kernel C: reduce 128 partials + bias -> out
__global__ __launch_bounds__(256)
void reduce_kernel(const float* __restrict__ partial,
                   const float* __restrict__ bias,
                   float* __restrict__ out)
{
    const int idx = blockIdx.x * 256 + threadIdx.x;   // 0..16383
    float s = bias[idx & (OUT_DIM - 1)];
    const float* p = partial + idx;
    #pragma unroll 8
    for (int kg = 0; kg < KGN; ++kg)
        s += p[(size_t)kg * (B_SZ * OUT_DIM)];
    out[idx] = s;
}

// ------------------------------------------------- fallback (proven v2 path)
__global__ __launch_bounds__(512, 2)
void qgemm_fallback_kernel(const float* __restrict__ x,
                           const float* __restrict__ W,
                           float* __restrict__ out)
{
    __shared__ float xt[B_SZ][512];

    const int tid  = threadIdx.x;
    const int lane = tid & 63;
    const int wave = tid >> 6;
    const int bgrp = wave & 3;
    const int ogrp = wave >> 2;

    const int og  = blockIdx.x & 31;
    const int kgf = blockIdx.x >> 5;

    const int o_base = og * 16 + ogrp * 8;
    const int b_base = bgrp * 8;

    float acc[8][8];
    #pragma unroll
    for (int i = 0; i < 8; ++i)
        #pragma unroll
        for (int o = 0; o < 8; ++o) acc[i][o] = 0.f;

    const int nch = (K_TOTAL + 511) / 512;
    for (int chunk = kgf; chunk < nch; chunk += 16) {
        const int k = chunk * 512 + tid;
        __syncthreads();
        if (k < IN_DIM) {
            #pragma unroll
            for (int b = 0; b < B_SZ; ++b)
                xt[b][tid] = x[b * IN_DIM + k];
        } else {
            const int t = k - IN_DIM;
            double disc = 4198401.0 - 8.0 * (double)t;
            int r = (int)((2049.0 - sqrt(disc)) * 0.5);
            int off = r * IN_DIM - ((r * (r - 1)) >> 1);
            if (t < off) { --r; off = r * IN_DIM - ((r * (r - 1)) >> 1); }
            else if (t >= off + (IN_DIM - r)) { off += IN_DIM - r; ++r; }
            const int ccol = r + (t - off);
            #pragma unroll
            for (int b = 0; b < B_SZ; ++b)
                xt[b][tid] = x[b * IN_DIM + r] * x[b * IN_DIM + ccol];
        }
        __syncthreads();

        const float* wrow = W + (size_t)o_base * K_TOTAL + (size_t)chunk * 512;
        #pragma unroll
        for (int pass = 0; pass < 2; ++pass) {
            const int kk = pass * 256 + lane * 4;
            float4 wv[8];
            #pragma unroll
            for (int o = 0; o < 8; ++o)
                wv[o] = *(const float4*)(wrow + (size_t)o * K_TOTAL + kk);
            float4 xv[8];
            #pragma unroll
            for (int i = 0; i < 8; ++i)
                xv[i] = *(const float4*)&xt[b_base + i][kk];
            #pragma unroll
            for (int o = 0; o < 8; ++o)
                #pragma unroll
                for (int i = 0; i < 8; ++i)
                    acc[i][o] += xv[i].x * wv[o].x + xv[i].y * wv[o].y
                               + xv[i].z * wv[o].z + xv[i].w * wv[o].w;
        }
    }

    #pragma unroll
    for (int i = 0; i < 8; ++i)
        #pragma unroll
        for (int o = 0; o < 8; ++o) {
            float v = acc[i][o];
            #pragma unroll
            for (int m = 1; m < 64; m <<= 1)
                v += __shfl_xor(v, m);
            acc[i][o] = v;
        }

    if (lane == 0) {
        #pragma unroll
        for (int i = 0; i < 8; ++i)
            #pragma unroll
            for (int o = 0; o < 8; ++o)
                atomicAdd(&out[(b_base + i) * OUT_DIM + o_base + o], acc[i][o]);
    }
}

extern "C" void kernel_launch(void* const* d_in, const int* in_sizes, int n_in,
                              void* d_out, int out_size, void* d_ws, size_t ws_size,
                              hipStream_t stream)
{
    const float* x    = (const float*)d_in[0];   // [32,1024] fp32
    const float* W    = (const float*)d_in[1];   // [512, 525824] fp32
    const float* bias = (const float*)d_in[2];   // [512] fp32
    float* out = (float*)d_out;                  // [32,512] fp32

    if (ws_size >= NEED_WS) {
        int4*  fpk  = (int4*)d_ws;
        float* part = (float*)((char*)d_ws + F_BYTES);
        hipLaunchKernelGGL(feat_pack_kernel, dim3(NCH), dim3(256), 0, stream, x, fpk);
        hipLaunchKernelGGL(qgemm_mfma_kernel, dim3(8 * KGN), dim3(256), 0, stream,
                           fpk, W, part);
        hipLaunchKernelGGL(reduce_kernel, dim3(64), dim3(256), 0, stream,
                           part, bias, out);
    } else {
        hipLaunchKernelGGL(bias_init_kernel, dim3(64), dim3(256), 0, stream, bias, out);
        hipLaunchKernelGGL(qgemm_fallback_kernel, dim3(512), dim3(512), 0, stream,
                           x, W, out);
    }
}

// Round 17
// 280.520 us; speedup vs baseline: 1.0766x; 1.0051x over previous
//
#include <hip/hip_runtime.h>
#include <hip/hip_bf16.h>

#define B_SZ     32
#define IN_DIM   1024
#define K_TOTAL  525824          // 1024 linear + 524800 triu = 4108 * 128
#define OUT_DIM  512
#define NCH      4108            // 128-k chunks
#define KGN      128             // k-segment groups (chunk stride)
#define F_BYTES  ((size_t)NCH * 8192)            // 33,652,736 packed bf16 features
#define P_ELEMS  ((size_t)KGN * B_SZ * OUT_DIM)  // 128 * 16384 partials
#define NEED_WS  (F_BYTES + P_ELEMS * 4)

typedef __attribute__((ext_vector_type(8))) short bfrag;   // 8 bf16 = 4 VGPR
typedef __attribute__((ext_vector_type(4))) float f32x4;

// async global->LDS, 16B per lane; LDS dest = wave-uniform base + lane*16,
// global source address is PER-LANE (swizzle goes on the source).
#define GLD16(g, l) __builtin_amdgcn_global_load_lds(                      \
    (const __attribute__((address_space(1))) void*)(g),                    \
    (__attribute__((address_space(3))) void*)(l), 16, 0, 0)

// fp32 -> bf16 round-to-nearest-even (pure integer)
__device__ inline unsigned bf16r(float f)
{
    unsigned u = __builtin_bit_cast(unsigned, f);
    return (u + 0x7FFFu + ((u >> 16) & 1u)) >> 16;
}
__device__ inline unsigned pk2(float a, float b)
{
    return bf16r(a) | (bf16r(b) << 16);
}

// ---------------------------------------------------------------- bias init (fallback path only)
__global__ void bias_init_kernel(const float* __restrict__ bias, float* __restrict__ out)
{
    int i = blockIdx.x * 256 + threadIdx.x;     // 16384 total
    out[i] = bias[i & (OUT_DIM - 1)];
}

// ------------- kernel A: feature expand -> bf16, MFMA-A-fragment packed
// layout: unit u = (chunk*16 + koctet)*32 + b holds f[b][chunk*128+koctet*8 .. +7]
__global__ __launch_bounds__(256)
void feat_pack_kernel(const float* __restrict__ x, int4* __restrict__ fp)
{
    const int chunk = blockIdx.x;               // 0..4107
    const int tid   = threadIdx.x;

    #pragma unroll
    for (int i = 0; i < 2; ++i) {
        const int unit = tid + i * 256;         // 0..511
        const int kb   = unit >> 5;             // k-octet 0..15
        const int b    = unit & 31;
        const int k0   = chunk * 128 + kb * 8;
        const float* xb = x + b * IN_DIM;

        float v[8];
        if (chunk < 8) {                        // linear features (k < 1024)
            #pragma unroll
            for (int e = 0; e < 8; ++e) v[e] = xb[k0 + e];
        } else {                                // quadratic: walk (r,c) from one sqrt
            int t = k0 - IN_DIM;
            float disc = 4198401.0f - 8.0f * (float)t;   // 2049^2 - 8t, exact in fp32
            int r = (int)((2049.0f - sqrtf(disc)) * 0.5f);
            int off = r * IN_DIM - ((r * (r - 1)) >> 1);
            if (t < off) { --r; off = r * IN_DIM - ((r * (r - 1)) >> 1); }
            else if (t >= off + (IN_DIM - r)) { off += IN_DIM - r; ++r; }
            int c_ = r + (t - off);
            #pragma unroll
            for (int e = 0; e < 8; ++e) {
                v[e] = xb[r] * xb[c_];
                if (c_ == IN_DIM - 1) { ++r; c_ = r; } else { ++c_; }
            }
        }
        int4 pk;
        pk.x = (int)pk2(v[0], v[1]);
        pk.y = (int)pk2(v[2], v[3]);
        pk.z = (int)pk2(v[4], v[5]);
        pk.w = (int)pk2(v[6], v[7]);
        fp[(size_t)chunk * 512 + unit] = pk;
    }
}

// ------------- kernel B: MFMA GEMM, W staged through LDS via global_load_lds.
// Each GLD16 reads 512B contiguous from each of 2 W rows (page-local bursts).
// W rows XOR-swizzled on the GLOBAL SOURCE (byte ^ ((row&7)<<4)); ds_read
// applies the same XOR. All staging is DMA: zero prefetch VGPR state.
// LDS = W 2x32KB + f 2x8KB = 80KB -> 2 blocks/CU. vmcnt(10) counted waits.
__global__ __launch_bounds__(256, 2)
void qgemm_mfma_kernel(const int4* __restrict__ fp,
                       const float* __restrict__ W,
                       float* __restrict__ partial)
{
    __shared__ int4 wlds[2][64][32];             // 64 KB (swizzled rows)
    __shared__ int4 fbuf[2][512];                // 16 KB

    const int tid  = threadIdx.x;
    const int lane = tid & 63;
    const int wv_  = tid >> 6;                   // 0..3
    const int lrow = lane & 15;                  // A row / B col within tile
    const int lkb  = lane >> 4;                  // k-octet group 0..3

    const int og = blockIdx.x >> 7;              // 0..7
    const int kg = blockIdx.x & (KGN - 1);       // 0..127 (bid%8 = kg%8: co-XCD f sharing)

    const int o_blk  = og * 64;
    const int o_base = o_blk + wv_ * 16;

    f32x4 acc0 = {0.f, 0.f, 0.f, 0.f};
    f32x4 acc1 = {0.f, 0.f, 0.f, 0.f};

    // stage W chunk cc into wlds[s]: 8 GLD16/wave, 2 rows x 512B each,
    // per-lane source pre-swizzled so linear LDS holds swizzled rows
    #define WSTAGE(s, cc)                                                       \
    do {                                                                        \
        _Pragma("unroll")                                                       \
        for (int j_ = 0; j_ < 8; ++j_) {                                        \
            const int rl_ = 2 * j_ + (lane >> 5);                               \
            const char* src_ = (const char*)(W                                  \
                + (size_t)(o_blk + wv_ * 16 + rl_) * K_TOTAL                    \
                + (size_t)(cc) * 128)                                           \
                + (((lane & 31) << 4) ^ ((rl_ & 7) << 4));                      \
            GLD16(src_, (char*)&wlds[s][wv_ * 16 + 2 * j_][0]);                 \
        }                                                                       \
    } while (0)

    // stage f chunk cc (8 KB linear) into fbuf[s]: 2 GLD16/wave
    #define FSTAGE(s, cc)                                                       \
    do {                                                                        \
        const char* gp_ = (const char*)fp + (size_t)(cc) * 8192                 \
                        + wv_ * 2048 + (size_t)(lane << 4);                     \
        GLD16(gp_,        (char*)&fbuf[s][0] + wv_ * 2048);                     \
        GLD16(gp_ + 1024, (char*)&fbuf[s][0] + wv_ * 2048 + 1024);              \
    } while (0)

    #define COMPUTE(s)                                                          \
    do {                                                                        \
        const int r_  = wv_ * 16 + lrow;                                        \
        const int s7_ = lrow & 7;                                               \
        _Pragma("unroll")                                                       \
        for (int q_ = 0; q_ < 4; ++q_) {                                        \
            const int sl_ = lkb * 2 + q_ * 8;                                   \
            const float4 f0_ = __builtin_bit_cast(float4, wlds[s][r_][sl_ ^ s7_]);       \
            const float4 f1_ = __builtin_bit_cast(float4, wlds[s][r_][(sl_ + 1) ^ s7_]); \
            int4 tw_;                                                           \
            tw_.x = (int)pk2(f0_.x, f0_.y);                                     \
            tw_.y = (int)pk2(f0_.z, f0_.w);                                     \
            tw_.z = (int)pk2(f1_.x, f1_.y);                                     \
            tw_.w = (int)pk2(f1_.z, f1_.w);                                     \
            const bfrag bw_ = __builtin_bit_cast(bfrag, tw_);                   \
            const int ub_ = (q_ * 4 + lkb) * 32 + lrow;                         \
            const bfrag a0_ = __builtin_bit_cast(bfrag, fbuf[s][ub_]);          \
            const bfrag a1_ = __builtin_bit_cast(bfrag, fbuf[s][ub_ + 16]);     \
            acc0 = __builtin_amdgcn_mfma_f32_16x16x32_bf16(a0_, bw_, acc0, 0, 0, 0); \
            acc1 = __builtin_amdgcn_mfma_f32_16x16x32_bf16(a1_, bw_, acc1, 0, 0, 0); \
        }                                                                       \
    } while (0)

    const int n = (kg < 12) ? 33 : 32;           // chunks owned: kg + t*128 < 4108
    int c = kg;

    WSTAGE(0, c);       FSTAGE(0, c);            // chunk 0: 10 DMA
    WSTAGE(1, c + KGN); FSTAGE(1, c + KGN);      // chunk 1: 20 in flight

    for (int t = 0; t < n; ++t) {
        if (t < n - 1)
            asm volatile("s_waitcnt vmcnt(10)" ::: "memory");  // chunk t landed
        else
            asm volatile("s_waitcnt vmcnt(0)" ::: "memory");   // last chunk
        __builtin_amdgcn_s_barrier();            // all waves' chunk-t data in LDS
        COMPUTE(t & 1);
        __builtin_amdgcn_s_barrier();            // all waves done reading buf[t&1]
        if (t + 2 < n) {
            WSTAGE(t & 1, c + 2 * KGN);          // overwrite with chunk t+2
            FSTAGE(t & 1, c + 2 * KGN);
        }
        c += KGN;
    }

    #undef COMPUTE
    #undef FSTAGE
    #undef WSTAGE

    // C layout: C[b = (lane>>4)*4 + reg][o = lane&15]; plain stores to partial[kg]
    float* pb = partial + (size_t)kg * (B_SZ * OUT_DIM) + o_base + lrow;
    const int r0 = lkb * 4;
    #pragma unroll
    for (int r = 0; r < 4; ++r) {
        pb[(size_t)(r0 + r) * OUT_DIM]      = acc0[r];
        pb[(size_t)(16 + r0 + r) * OUT_DIM] = acc1[r];
    }
}

// ------------- kernel C: reduce 128 partials + bias -> out
__global__ __launch_bounds__(256)
void reduce_kernel(const float* __restrict__ partial,
                   const float* __restrict__ bias,
                   float* __restrict__ out)
{
    const int idx = blockIdx.x * 256 + threadIdx.x;   // 0..16383
    float s = bias[idx & (OUT_DIM - 1)];
    const float* p = partial + idx;
    #pragma unroll 8
    for (int kg = 0; kg < KGN; ++kg)
        s += p[(size_t)kg * (B_SZ * OUT_DIM)];
    out[idx] = s;
}

// ------------------------------------------------- fallback (proven v2 path)
__global__ __launch_bounds__(512, 2)
void qgemm_fallback_kernel(const float* __restrict__ x,
                           const float* __restrict__ W,
                           float* __restrict__ out)
{
    __shared__ float xt[B_SZ][512];

    const int tid  = threadIdx.x;
    const int lane = tid & 63;
    const int wave = tid >> 6;
    const int bgrp = wave & 3;
    const int ogrp = wave >> 2;

    const int og  = blockIdx.x & 31;
    const int kgf = blockIdx.x >> 5;

    const int o_base = og * 16 + ogrp * 8;
    const int b_base = bgrp * 8;

    float acc[8][8];
    #pragma unroll
    for (int i = 0; i < 8; ++i)
        #pragma unroll
        for (int o = 0; o < 8; ++o) acc[i][o] = 0.f;

    const int nch = (K_TOTAL + 511) / 512;
    for (int chunk = kgf; chunk < nch; chunk += 16) {
        const int k = chunk * 512 + tid;
        __syncthreads();
        if (k < IN_DIM) {
            #pragma unroll
            for (int b = 0; b < B_SZ; ++b)
                xt[b][tid] = x[b * IN_DIM + k];
        } else {
            const int t = k - IN_DIM;
            double disc = 4198401.0 - 8.0 * (double)t;
            int r = (int)((2049.0 - sqrt(disc)) * 0.5);
            int off = r * IN_DIM - ((r * (r - 1)) >> 1);
            if (t < off) { --r; off = r * IN_DIM - ((r * (r - 1)) >> 1); }
            else if (t >= off + (IN_DIM - r)) { off += IN_DIM - r; ++r; }
            const int ccol = r + (t - off);
            #pragma unroll
            for (int b = 0; b < B_SZ; ++b)
                xt[b][tid] = x[b * IN_DIM + r] * x[b * IN_DIM + ccol];
        }
        __syncthreads();

        const float* wrow = W + (size_t)o_base * K_TOTAL + (size_t)chunk * 512;
        #pragma unroll
        for (int pass = 0; pass < 2; ++pass) {
            const int kk = pass * 256 + lane * 4;
            float4 wv[8];
            #pragma unroll
            for (int o = 0; o < 8; ++o)
                wv[o] = *(const float4*)(wrow + (size_t)o * K_TOTAL + kk);
            float4 xv[8];
            #pragma unroll
            for (int i = 0; i < 8; ++i)
                xv[i] = *(const float4*)&xt[b_base + i][kk];
            #pragma unroll
            for (int o = 0; o < 8; ++o)
                #pragma unroll
                for (int i = 0; i < 8; ++i)
                    acc[i][o] += xv[i].x * wv[o].x + xv[i].y * wv[o].y
                               + xv[i].z * wv[o].z + xv[i].w * wv[o].w;
        }
    }

    #pragma unroll
    for (int i = 0; i < 8; ++i)
        #pragma unroll
        for (int o = 0; o < 8; ++o) {
            float v = acc[i][o];
            #pragma unroll
            for (int m = 1; m < 64; m <<= 1)
                v += __shfl_xor(v, m);
            acc[i][o] = v;
        }

    if (lane == 0) {
        #pragma unroll
        for (int i = 0; i < 8; ++i)
            #pragma unroll
            for (int o = 0; o < 8; ++o)
                atomicAdd(&out[(b_base + i) * OUT_DIM + o_base + o], acc[i][o]);
    }
}

extern "C" void kernel_launch(void* const* d_in, const int* in_sizes, int n_in,
                              void* d_out, int out_size, void* d_ws, size_t ws_size,
                              hipStream_t stream)
{
    const float* x    = (const float*)d_in[0];   // [32,1024] fp32
    const float* W    = (const float*)d_in[1];   // [512, 525824] fp32
    const float* bias = (const float*)d_in[2];   // [512] fp32
    float* out = (float*)d_out;                  // [32,512] fp32

    if (ws_size >= NEED_WS) {
        int4*  fpk  = (int4*)d_ws;
        float* part = (float*)((char*)d_ws + F_BYTES);
        hipLaunchKernelGGL(feat_pack_kernel, dim3(NCH), dim3(256), 0, stream, x, fpk);
        hipLaunchKernelGGL(qgemm_mfma_kernel, dim3(8 * KGN), dim3(256), 0, stream,
                           fpk, W, part);
        hipLaunchKernelGGL(reduce_kernel, dim3(64), dim3(256), 0, stream,
                           part, bias, out);
    } else {
        hipLaunchKernelGGL(bias_init_kernel, dim3(64), dim3(256), 0, stream, bias, out);
        hipLaunchKernelGGL(qgemm_fallback_kernel, dim3(512), dim3(512), 0, stream,
                           x, W, out);
    }
}

// Round 18
// 256.694 us; speedup vs baseline: 1.1765x; 1.0928x over previous
//
#include <hip/hip_runtime.h>
#include <hip/hip_bf16.h>

#define B_SZ     32
#define IN_DIM   1024
#define K_TOTAL  525824          // 1024 linear + 524800 triu = 4108 * 128
#define OUT_DIM  512
#define NCH      4108            // 128-k chunks
#define KGN      128             // k-segment groups (chunk stride)
#define P_BYTES  ((size_t)KGN * B_SZ * OUT_DIM * 4)   // 8.4 MB partials
#define XT_BYTES ((size_t)IN_DIM * B_SZ * 4)          // 128 KB transposed x
#define NEED_WS  (P_BYTES + XT_BYTES)

typedef __attribute__((ext_vector_type(8))) short bfrag;   // 8 bf16 = 4 VGPR
typedef __attribute__((ext_vector_type(4))) float f32x4;

// async global->LDS, 16B per lane; LDS dest = wave-uniform base + lane*16,
// global source address is PER-LANE (swizzle goes on the source).
#define GLD16(g, l) __builtin_amdgcn_global_load_lds(                      \
    (const __attribute__((address_space(1))) void*)(g),                    \
    (__attribute__((address_space(3))) void*)(l), 16, 0, 0)

// fp32 -> bf16 round-to-nearest-even (pure integer)
__device__ inline unsigned bf16r(float f)
{
    unsigned u = __builtin_bit_cast(unsigned, f);
    return (u + 0x7FFFu + ((u >> 16) & 1u)) >> 16;
}
__device__ inline unsigned pk2(float a, float b)
{
    return bf16r(a) | (bf16r(b) << 16);
}

// ---------------------------------------------------------------- bias init (fallback path only)
__global__ void bias_init_kernel(const float* __restrict__ bias, float* __restrict__ out)
{
    int i = blockIdx.x * 256 + threadIdx.x;     // 16384 total
    out[i] = bias[i & (OUT_DIM - 1)];
}

// ------------- kernel A: transpose x -> xT[k][b] (128 KB, L2-resident)
__global__ __launch_bounds__(256)
void xpose_kernel(const float* __restrict__ x, float* __restrict__ xT)
{
    const int idx = blockIdx.x * 256 + threadIdx.x;   // 0..32767
    const int k = idx >> 5, b = idx & 31;
    xT[idx] = x[b * IN_DIM + k];                      // write coalesced
}

// ------------- kernel B: fused MFMA GEMM. W staged via global_load_lds
// (512B/row bursts, source-XOR-swizzled rows); f fragments COMPUTED on the
// fly from xT into fbuf via ds_write (bit-identical to the old feat_pack).
// Split-K partial store; 2 blocks/CU (80 KB LDS).
__global__ __launch_bounds__(256, 2)
void qgemm_mfma_kernel(const float* __restrict__ xT,
                       const float* __restrict__ W,
                       float* __restrict__ partial)
{
    __shared__ int4 wlds[2][64][32];             // 64 KB (swizzled rows)
    __shared__ int4 fbuf[2][512];                // 16 KB

    const int tid  = threadIdx.x;
    const int lane = tid & 63;
    const int wv_  = tid >> 6;                   // 0..3
    const int lrow = lane & 15;                  // A row / B col within tile
    const int lkb  = lane >> 4;                  // k-octet group 0..3

    const int og = blockIdx.x >> 7;              // 0..7
    const int kg = blockIdx.x & (KGN - 1);       // 0..127 (bid%8 = kg%8 co-XCD)

    const int o_blk  = og * 64;
    const int o_base = o_blk + wv_ * 16;

    f32x4 acc0 = {0.f, 0.f, 0.f, 0.f};
    f32x4 acc1 = {0.f, 0.f, 0.f, 0.f};

    // stage W chunk cc into wlds[s]: 8 GLD16/wave, 2 rows x 512B each,
    // per-lane source pre-swizzled so linear LDS holds swizzled rows
    #define WSTAGE(s, cc)                                                       \
    do {                                                                        \
        _Pragma("unroll")                                                       \
        for (int j_ = 0; j_ < 8; ++j_) {                                        \
            const int rl_ = 2 * j_ + (lane >> 5);                               \
            const char* src_ = (const char*)(W                                  \
                + (size_t)(o_blk + wv_ * 16 + rl_) * K_TOTAL                    \
                + (size_t)(cc) * 128)                                           \
                + (((lane & 31) << 4) ^ ((rl_ & 7) << 4));                      \
            GLD16(src_, (char*)&wlds[s][wv_ * 16 + 2 * j_][0]);                 \
        }                                                                       \
    } while (0)

    // compute f chunk cc directly into fbuf[s] (2 units/thread, ds_write_b128)
    #define FCOMP(s, cc)                                                        \
    do {                                                                        \
        _Pragma("unroll")                                                       \
        for (int i_ = 0; i_ < 2; ++i_) {                                        \
            const int u_  = tid + i_ * 256;      /* unit = koctet*32 + b */     \
            const int kb_ = u_ >> 5;                                            \
            const int b_  = u_ & 31;                                            \
            const int k0_ = (cc) * 128 + kb_ * 8;                               \
            float v_[8];                                                        \
            if (k0_ < IN_DIM) {                                                 \
                _Pragma("unroll")                                               \
                for (int e_ = 0; e_ < 8; ++e_)                                  \
                    v_[e_] = xT[(k0_ + e_) * B_SZ + b_];                        \
            } else {                                                            \
                int t_ = k0_ - IN_DIM;                                          \
                float disc_ = 4198401.0f - 8.0f * (float)t_;                    \
                int r_ = (int)((2049.0f - sqrtf(disc_)) * 0.5f);                \
                int off_ = r_ * IN_DIM - ((r_ * (r_ - 1)) >> 1);                \
                if (t_ < off_) { --r_; off_ = r_ * IN_DIM - ((r_ * (r_ - 1)) >> 1); } \
                else if (t_ >= off_ + (IN_DIM - r_)) { off_ += IN_DIM - r_; ++r_; }   \
                int c2_ = r_ + (t_ - off_);                                     \
                _Pragma("unroll")                                               \
                for (int e_ = 0; e_ < 8; ++e_) {                                \
                    v_[e_] = xT[r_ * B_SZ + b_] * xT[c2_ * B_SZ + b_];          \
                    if (c2_ == IN_DIM - 1) { ++r_; c2_ = r_; } else { ++c2_; }  \
                }                                                               \
            }                                                                   \
            int4 pk_;                                                           \
            pk_.x = (int)pk2(v_[0], v_[1]);                                     \
            pk_.y = (int)pk2(v_[2], v_[3]);                                     \
            pk_.z = (int)pk2(v_[4], v_[5]);                                     \
            pk_.w = (int)pk2(v_[6], v_[7]);                                     \
            fbuf[s][u_] = pk_;                                                  \
        }                                                                       \
    } while (0)

    #define COMPUTE(s)                                                          \
    do {                                                                        \
        const int r_  = wv_ * 16 + lrow;                                        \
        const int s7_ = lrow & 7;                                               \
        _Pragma("unroll")                                                       \
        for (int q_ = 0; q_ < 4; ++q_) {                                        \
            const int sl_ = lkb * 2 + q_ * 8;                                   \
            const float4 f0_ = __builtin_bit_cast(float4, wlds[s][r_][sl_ ^ s7_]);       \
            const float4 f1_ = __builtin_bit_cast(float4, wlds[s][r_][(sl_ + 1) ^ s7_]); \
            int4 tw_;                                                           \
            tw_.x = (int)pk2(f0_.x, f0_.y);                                     \
            tw_.y = (int)pk2(f0_.z, f0_.w);                                     \
            tw_.z = (int)pk2(f1_.x, f1_.y);                                     \
            tw_.w = (int)pk2(f1_.z, f1_.w);                                     \
            const bfrag bw_ = __builtin_bit_cast(bfrag, tw_);                   \
            const int ub_ = (q_ * 4 + lkb) * 32 + lrow;                         \
            const bfrag a0_ = __builtin_bit_cast(bfrag, fbuf[s][ub_]);          \
            const bfrag a1_ = __builtin_bit_cast(bfrag, fbuf[s][ub_ + 16]);     \
            acc0 = __builtin_amdgcn_mfma_f32_16x16x32_bf16(a0_, bw_, acc0, 0, 0, 0); \
            acc1 = __builtin_amdgcn_mfma_f32_16x16x32_bf16(a1_, bw_, acc1, 0, 0, 0); \
        }                                                                       \
    } while (0)

    const int n = (kg < 12) ? 33 : 32;           // chunks owned: kg + t*128 < 4108
    int c = kg;

    WSTAGE(0, c);                                // 8 DMA
    WSTAGE(1, c + KGN);                          // 16 in flight
    FCOMP(0, c);
    FCOMP(1, c + KGN);

    for (int t = 0; t < n; ++t) {
        if (t < n - 1)
            asm volatile("s_waitcnt vmcnt(8) lgkmcnt(0)" ::: "memory");  // W(t) landed, f writes visible
        else
            asm volatile("s_waitcnt vmcnt(0) lgkmcnt(0)" ::: "memory");
        __builtin_amdgcn_s_barrier();            // all waves' chunk-t data in LDS
        COMPUTE(t & 1);
        __builtin_amdgcn_s_barrier();            // all waves done reading buf[t&1]
        if (t + 2 < n) {
            WSTAGE(t & 1, c + 2 * KGN);          // overwrite with chunk t+2
            FCOMP(t & 1, c + 2 * KGN);
        }
        c += KGN;
    }

    #undef COMPUTE
    #undef FCOMP
    #undef WSTAGE

    // C layout: C[b = (lane>>4)*4 + reg][o = lane&15]; plain stores to partial[kg]
    float* pb = partial + (size_t)kg * (B_SZ * OUT_DIM) + o_base + lrow;
    const int r0 = lkb * 4;
    #pragma unroll
    for (int r = 0; r < 4; ++r) {
        pb[(size_t)(r0 + r) * OUT_DIM]      = acc0[r];
        pb[(size_t)(16 + r0 + r) * OUT_DIM] = acc1[r];
    }
}

// ------------- kernel C: reduce 128 partials + bias -> out
__global__ __launch_bounds__(256)
void reduce_kernel(const float* __restrict__ partial,
                   const float* __restrict__ bias,
                   float* __restrict__ out)
{
    const int idx = blockIdx.x * 256 + threadIdx.x;   // 0..16383
    float s = bias[idx & (OUT_DIM - 1)];
    const float* p = partial + idx;
    #pragma unroll 8
    for (int kg = 0; kg < KGN; ++kg)
        s += p[(size_t)kg * (B_SZ * OUT_DIM)];
    out[idx] = s;
}

// ------------------------------------------------- fallback (proven v2 path)
__global__ __launch_bounds__(512, 2)
void qgemm_fallback_kernel(const float* __restrict__ x,
                           const float* __restrict__ W,
                           float* __restrict__ out)
{
    __shared__ float xt[B_SZ][512];

    const int tid  = threadIdx.x;
    const int lane = tid & 63;
    const int wave = tid >> 6;
    const int bgrp = wave & 3;
    const int ogrp = wave >> 2;

    const int og  = blockIdx.x & 31;
    const int kgf = blockIdx.x >> 5;

    const int o_base = og * 16 + ogrp * 8;
    const int b_base = bgrp * 8;

    float acc[8][8];
    #pragma unroll
    for (int i = 0; i < 8; ++i)
        #pragma unroll
        for (int o = 0; o < 8; ++o) acc[i][o] = 0.f;

    const int nch = (K_TOTAL + 511) / 512;
    for (int chunk = kgf; chunk < nch; chunk += 16) {
        const int k = chunk * 512 + tid;
        __syncthreads();
        if (k < IN_DIM) {
            #pragma unroll
            for (int b = 0; b < B_SZ; ++b)
                xt[b][tid] = x[b * IN_DIM + k];
        } else {
            const int t = k - IN_DIM;
            double disc = 4198401.0 - 8.0 * (double)t;
            int r = (int)((2049.0 - sqrt(disc)) * 0.5);
            int off = r * IN_DIM - ((r * (r - 1)) >> 1);
            if (t < off) { --r; off = r * IN_DIM - ((r * (r - 1)) >> 1); }
            else if (t >= off + (IN_DIM - r)) { off += IN_DIM - r; ++r; }
            const int ccol = r + (t - off);
            #pragma unroll
            for (int b = 0; b < B_SZ; ++b)
                xt[b][tid] = x[b * IN_DIM + r] * x[b * IN_DIM + ccol];
        }
        __syncthreads();

        const float* wrow = W + (size_t)o_base * K_TOTAL + (size_t)chunk * 512;
        #pragma unroll
        for (int pass = 0; pass < 2; ++pass) {
            const int kk = pass * 256 + lane * 4;
            float4 wv[8];
            #pragma unroll
            for (int o = 0; o < 8; ++o)
                wv[o] = *(const float4*)(wrow + (size_t)o * K_TOTAL + kk);
            float4 xv[8];
            #pragma unroll
            for (int i = 0; i < 8; ++i)
                xv[i] = *(const float4*)&xt[b_base + i][kk];
            #pragma unroll
            for (int o = 0; o < 8; ++o)
                #pragma unroll
                for (int i = 0; i < 8; ++i)
                    acc[i][o] += xv[i].x * wv[o].x + xv[i].y * wv[o].y
                               + xv[i].z * wv[o].z + xv[i].w * wv[o].w;
        }
    }

    #pragma unroll
    for (int i = 0; i < 8; ++i)
        #pragma unroll
        for (int o = 0; o < 8; ++o) {
            float v = acc[i][o];
            #pragma unroll
            for (int m = 1; m < 64; m <<= 1)
                v += __shfl_xor(v, m);
            acc[i][o] = v;
        }

    if (lane == 0) {
        #pragma unroll
        for (int i = 0; i < 8; ++i)
            #pragma unroll
            for (int o = 0; o < 8; ++o)
                atomicAdd(&out[(b_base + i) * OUT_DIM + o_base + o], acc[i][o]);
    }
}

extern "C" void kernel_launch(void* const* d_in, const int* in_sizes, int n_in,
                              void* d_out, int out_size, void* d_ws, size_t ws_size,
                              hipStream_t stream)
{
    const float* x    = (const float*)d_in[0];   // [32,1024] fp32
    const float* W    = (const float*)d_in[1];   // [512, 525824] fp32
    const float* bias = (const float*)d_in[2];   // [512] fp32
    float* out = (float*)d_out;                  // [32,512] fp32

    if (ws_size >= NEED_WS) {
        float* part = (float*)d_ws;
        float* xT   = (float*)((char*)d_ws + P_BYTES);
        hipLaunchKernelGGL(xpose_kernel, dim3(128), dim3(256), 0, stream, x, xT);
        hipLaunchKernelGGL(qgemm_mfma_kernel, dim3(8 * KGN), dim3(256), 0, stream,
                           xT, W, part);
        hipLaunchKernelGGL(reduce_kernel, dim3(64), dim3(256), 0, stream,
                           part, bias, out);
    } else {
        hipLaunchKernelGGL(bias_init_kernel, dim3(64), dim3(256), 0, stream, bias, out);
        hipLaunchKernelGGL(qgemm_fallback_kernel, dim3(512), dim3(512), 0, stream,
                           x, W, out);
    }
}